// Round 1
// baseline (3348.880 us; speedup 1.0000x reference)
//
#include <hip/hip_runtime.h>

#define EPS 1e-5f

// ---------------- zero workspace ----------------
__global__ __launch_bounds__(256) void zero_kernel(float* __restrict__ p, long n) {
    long i = (long)blockIdx.x * blockDim.x + threadIdx.x;
    long stride = (long)gridDim.x * blockDim.x;
    long n4 = n >> 2;
    float4* p4 = (float4*)p;
    for (long k = i; k < n4; k += stride) p4[k] = make_float4(0.f, 0.f, 0.f, 0.f);
    for (long k = (n4 << 2) + i; k < n; k += stride) p[k] = 0.f;
}

// ---------------- edge stage: m = LN(relu([x[row], eattr] @ W1 + b1)); scatter-add ----------------
// 256 threads = 4 waves; one edge per wave per iteration (grid-stride).
__global__ __launch_bounds__(256) void edge_kernel(
    const float* __restrict__ x_h, const int* __restrict__ eidx,
    const float* __restrict__ eattr,
    const float* __restrict__ W1, const float* __restrict__ b1,
    const float* __restrict__ g1, const float* __restrict__ be1,
    float* __restrict__ summed, float* __restrict__ cnt,
    int E, int N)
{
    __shared__ float sW[128 * 64];      // 32 KB
    __shared__ float sb[64], sg[64], sbe[64];
    for (int t = threadIdx.x; t < 128 * 64; t += 256) sW[t] = W1[t];
    if (threadIdx.x < 64) {
        sb[threadIdx.x]  = b1[threadIdx.x];
        sg[threadIdx.x]  = g1[threadIdx.x];
        sbe[threadIdx.x] = be1[threadIdx.x];
    }
    __syncthreads();

    const int lane = threadIdx.x & 63;
    const int wid  = threadIdx.x >> 6;

    for (int e = blockIdx.x * 4 + wid; e < E; e += gridDim.x * 4) {
        int row = eidx[e];
        int col = eidx[E + e];
        float xv = x_h[(long)row * 64 + lane];
        float ev = eattr[(long)e * 64 + lane];

        float acc = sb[lane];
        #pragma unroll
        for (int i = 0; i < 64; ++i) acc += __shfl(xv, i) * sW[i * 64 + lane];
        #pragma unroll
        for (int i = 0; i < 64; ++i) acc += __shfl(ev, i) * sW[(64 + i) * 64 + lane];

        acc = fmaxf(acc, 0.f);                       // relu
        // LayerNorm across the 64 lanes
        float s1 = acc, s2 = acc * acc;
        #pragma unroll
        for (int m = 32; m; m >>= 1) { s1 += __shfl_xor(s1, m); s2 += __shfl_xor(s2, m); }
        float mu  = s1 * (1.f / 64.f);
        float var = s2 * (1.f / 64.f) - mu * mu;
        float v = (acc - mu) * rsqrtf(var + EPS) * sg[lane] + sbe[lane];

        atomicAdd(&summed[(long)col * 64 + lane], v);
        if (lane == 0) atomicAdd(&cnt[col], 1.0f);
    }
}

// ---------------- node stage: h=LN(relu([x,agg,u]@W2+b2)); h=LN(h@W3+b3); out=h+x ----------------
__global__ __launch_bounds__(256) void node_kernel(
    const float* __restrict__ x_h, const float* __restrict__ u,
    const float* __restrict__ W2, const float* __restrict__ b2,
    const float* __restrict__ g2, const float* __restrict__ be2,
    const float* __restrict__ W3, const float* __restrict__ b3,
    const float* __restrict__ g3, const float* __restrict__ be3,
    const float* __restrict__ summed, const float* __restrict__ cnt,
    float* __restrict__ out, int N)
{
    __shared__ float sW2[129 * 64];     // 33 KB
    __shared__ float sW3[64 * 64];      // 16 KB
    __shared__ float sv[6 * 64];        // b2,g2,be2,b3,g3,be3
    for (int t = threadIdx.x; t < 129 * 64; t += 256) sW2[t] = W2[t];
    for (int t = threadIdx.x; t < 64 * 64; t += 256) sW3[t] = W3[t];
    if (threadIdx.x < 64) {
        int j = threadIdx.x;
        sv[j]       = b2[j]; sv[64 + j]  = g2[j]; sv[128 + j] = be2[j];
        sv[192 + j] = b3[j]; sv[256 + j] = g3[j]; sv[320 + j] = be3[j];
    }
    __syncthreads();

    const float u0 = u[0];
    const int lane = threadIdx.x & 63;
    const int wid  = threadIdx.x >> 6;

    for (int n = blockIdx.x * 4 + wid; n < N; n += gridDim.x * 4) {
        float xv = x_h[(long)n * 64 + lane];
        float c  = fmaxf(cnt[n], 1.f);
        float av = summed[(long)n * 64 + lane] / c;

        // layer 2: [x (64) | agg (64) | u (1)] @ W2 + b2
        float acc = sv[lane] + u0 * sW2[128 * 64 + lane];
        #pragma unroll
        for (int i = 0; i < 64; ++i) acc += __shfl(xv, i) * sW2[i * 64 + lane];
        #pragma unroll
        for (int i = 0; i < 64; ++i) acc += __shfl(av, i) * sW2[(64 + i) * 64 + lane];
        acc = fmaxf(acc, 0.f);
        float s1 = acc, s2 = acc * acc;
        #pragma unroll
        for (int m = 32; m; m >>= 1) { s1 += __shfl_xor(s1, m); s2 += __shfl_xor(s2, m); }
        float mu  = s1 * (1.f / 64.f);
        float var = s2 * (1.f / 64.f) - mu * mu;
        float h2 = (acc - mu) * rsqrtf(var + EPS) * sv[64 + lane] + sv[128 + lane];

        // layer 3: h2 @ W3 + b3, LN (no relu)
        float acc3 = sv[192 + lane];
        #pragma unroll
        for (int i = 0; i < 64; ++i) acc3 += __shfl(h2, i) * sW3[i * 64 + lane];
        s1 = acc3; s2 = acc3 * acc3;
        #pragma unroll
        for (int m = 32; m; m >>= 1) { s1 += __shfl_xor(s1, m); s2 += __shfl_xor(s2, m); }
        mu  = s1 * (1.f / 64.f);
        var = s2 * (1.f / 64.f) - mu * mu;
        float h3 = (acc3 - mu) * rsqrtf(var + EPS) * sv[256 + lane] + sv[320 + lane];

        out[(long)n * 64 + lane] = h3 + xv;
    }
}

extern "C" void kernel_launch(void* const* d_in, const int* in_sizes, int n_in,
                              void* d_out, int out_size, void* d_ws, size_t ws_size,
                              hipStream_t stream)
{
    const float* x_h   = (const float*)d_in[0];
    const int*   eidx  = (const int*)  d_in[1];
    const float* eattr = (const float*)d_in[2];
    const float* u     = (const float*)d_in[3];
    // d_in[4] = batch (all zeros, B=1) -> unused
    const float* W1  = (const float*)d_in[5];
    const float* b1  = (const float*)d_in[6];
    const float* g1  = (const float*)d_in[7];
    const float* be1 = (const float*)d_in[8];
    const float* W2  = (const float*)d_in[9];
    const float* b2  = (const float*)d_in[10];
    const float* g2  = (const float*)d_in[11];
    const float* be2 = (const float*)d_in[12];
    const float* W3  = (const float*)d_in[13];
    const float* b3  = (const float*)d_in[14];
    const float* g3  = (const float*)d_in[15];
    const float* be3 = (const float*)d_in[16];

    const int N = in_sizes[0] / 64;
    const int E = in_sizes[1] / 2;

    float* summed = (float*)d_ws;                 // N*64 floats
    float* cnt    = summed + (size_t)N * 64;      // N floats

    long zn = (long)N * 64 + N;
    zero_kernel<<<1024, 256, 0, stream>>>(summed, zn);

    int eblocks = 1024;                           // 4 blocks/CU (LDS-capped), W1 loaded once/block
    edge_kernel<<<eblocks, 256, 0, stream>>>(x_h, eidx, eattr, W1, b1, g1, be1,
                                             summed, cnt, E, N);

    int nblocks = 1024;
    node_kernel<<<nblocks, 256, 0, stream>>>(x_h, u, W2, b2, g2, be2, W3, b3, g3, be3,
                                             summed, cnt, (float*)d_out, N);
}

// Round 2
// 1008.414 us; speedup vs baseline: 3.3209x; 3.3209x over previous
//
#include <hip/hip_runtime.h>

#define EPS 1e-5f

typedef __attribute__((ext_vector_type(8))) short short8v;
typedef __attribute__((ext_vector_type(4))) float f32x4;

__device__ __forceinline__ unsigned short f2bf(float f) {
    unsigned u = __builtin_bit_cast(unsigned, f);
    u += 0x7fffu + ((u >> 16) & 1u);
    return (unsigned short)(u >> 16);
}

// ---------------- zero workspace ----------------
__global__ __launch_bounds__(256) void zero_kernel(float* __restrict__ p, long n) {
    long i = (long)blockIdx.x * blockDim.x + threadIdx.x;
    long stride = (long)gridDim.x * blockDim.x;
    long n4 = n >> 2;
    float4* p4 = (float4*)p;
    for (long k = i; k < n4; k += stride) p4[k] = make_float4(0.f, 0.f, 0.f, 0.f);
    for (long k = (n4 << 2) + i; k < n; k += stride) p[k] = 0.f;
}

// ---------------- edge stage (MFMA): m = LN(relu([x[row], eattr] @ W1 + b1)); scatter-add ----
// 256 threads = 4 waves; each wave computes 64 edges x 64 outputs per iteration via
// 16x16x32 bf16 MFMA. A-frag: row=lane&15, k=(lane>>4)*8+j. B-frag: col=lane&15, same k.
// C-frag: col=lane&15, row=(lane>>4)*4+reg  [verified layout, learn_hip m89].
__global__ __launch_bounds__(256) void edge_kernel(
    const float* __restrict__ x_h, const int* __restrict__ eidx,
    const float* __restrict__ eattr,
    const float* __restrict__ W1, const float* __restrict__ b1,
    const float* __restrict__ g1, const float* __restrict__ be1,
    float* __restrict__ summed, float* __restrict__ cnt,
    int E, int N)
{
    const int lane = threadIdx.x & 63;
    const int wid  = threadIdx.x >> 6;
    const int c = lane & 15;
    const int q = lane >> 4;

    // B fragments: W1[k][n] fp32 row-major [128][64]; lane holds k=ks*32+q*8+j, n=nt*16+c.
    short8v w1f[4][4];
    #pragma unroll
    for (int ks = 0; ks < 4; ++ks) {
        #pragma unroll
        for (int nt = 0; nt < 4; ++nt) {
            int k0 = ks * 32 + q * 8;
            int n  = nt * 16 + c;
            short8v f;
            #pragma unroll
            for (int j = 0; j < 8; ++j) f[j] = (short)f2bf(W1[(k0 + j) * 64 + n]);
            w1f[ks][nt] = f;
        }
    }
    float b1v[4], g1v[4], bev[4];
    #pragma unroll
    for (int nt = 0; nt < 4; ++nt) {
        b1v[nt] = b1[nt * 16 + c];
        g1v[nt] = g1[nt * 16 + c];
        bev[nt] = be1[nt * 16 + c];
    }

    for (long e0 = (long)blockIdx.x * 256 + wid * 64; e0 < E; e0 += (long)gridDim.x * 256) {
        // per-edge count atomic (one lane per edge, coalesced eidx load)
        {
            long el = e0 + lane;
            if (el < E) atomicAdd(&cnt[eidx[E + el]], 1.f);
        }

        f32x4 acc[4][4];
        #pragma unroll
        for (int mt = 0; mt < 4; ++mt)
            #pragma unroll
            for (int nt = 0; nt < 4; ++nt)
                acc[mt][nt] = (f32x4){0.f, 0.f, 0.f, 0.f};

        #pragma unroll
        for (int mt = 0; mt < 4; ++mt) {
            long er = e0 + mt * 16 + c;
            long ec = (er < E) ? er : (E - 1);
            int src = eidx[ec];
            const float* xp = x_h + (long)src * 64;
            const float* ep = eattr + ec * 64;
            #pragma unroll
            for (int ks = 0; ks < 4; ++ks) {
                int k0 = ks * 32 + q * 8;
                const float* base = (ks < 2) ? (xp + k0) : (ep + (k0 - 64));
                float4 lo = *(const float4*)(base);
                float4 hi = *(const float4*)(base + 4);
                short8v a;
                a[0] = (short)f2bf(lo.x); a[1] = (short)f2bf(lo.y);
                a[2] = (short)f2bf(lo.z); a[3] = (short)f2bf(lo.w);
                a[4] = (short)f2bf(hi.x); a[5] = (short)f2bf(hi.y);
                a[6] = (short)f2bf(hi.z); a[7] = (short)f2bf(hi.w);
                #pragma unroll
                for (int nt = 0; nt < 4; ++nt)
                    acc[mt][nt] = __builtin_amdgcn_mfma_f32_16x16x32_bf16(
                        a, w1f[ks][nt], acc[mt][nt], 0, 0, 0);
            }
        }

        // epilogue: bias + relu + LayerNorm (row = edge) + atomic scatter
        #pragma unroll
        for (int mt = 0; mt < 4; ++mt) {
            float s1[4] = {0, 0, 0, 0}, s2[4] = {0, 0, 0, 0};
            #pragma unroll
            for (int nt = 0; nt < 4; ++nt) {
                #pragma unroll
                for (int r = 0; r < 4; ++r) {
                    float f = fmaxf(acc[mt][nt][r] + b1v[nt], 0.f);
                    acc[mt][nt][r] = f;
                    s1[r] += f; s2[r] += f * f;
                }
            }
            // reduce across the 16 col-lanes (low 4 lane bits); q bits untouched
            #pragma unroll
            for (int m = 1; m <= 8; m <<= 1) {
                #pragma unroll
                for (int r = 0; r < 4; ++r) {
                    s1[r] += __shfl_xor(s1[r], m);
                    s2[r] += __shfl_xor(s2[r], m);
                }
            }
            float mu[4], rs[4]; int dst[4];
            #pragma unroll
            for (int r = 0; r < 4; ++r) {
                mu[r] = s1[r] * (1.f / 64.f);
                float var = s2[r] * (1.f / 64.f) - mu[r] * mu[r];
                rs[r] = rsqrtf(var + EPS);
                long er = e0 + mt * 16 + q * 4 + r;
                dst[r] = (er < E) ? eidx[E + er] : -1;   // broadcast load (16 lanes share addr)
            }
            #pragma unroll
            for (int nt = 0; nt < 4; ++nt) {
                #pragma unroll
                for (int r = 0; r < 4; ++r) {
                    if (dst[r] >= 0) {
                        float outv = (acc[mt][nt][r] - mu[r]) * rs[r] * g1v[nt] + bev[nt];
                        atomicAdd(&summed[(long)dst[r] * 64 + nt * 16 + c], outv);
                    }
                }
            }
        }
    }
}

// ---------------- node stage (unchanged, known-correct): h=LN(relu([x,agg,u]@W2+b2)); h=LN(h@W3+b3); out=h+x ----
__global__ __launch_bounds__(256) void node_kernel(
    const float* __restrict__ x_h, const float* __restrict__ u,
    const float* __restrict__ W2, const float* __restrict__ b2,
    const float* __restrict__ g2, const float* __restrict__ be2,
    const float* __restrict__ W3, const float* __restrict__ b3,
    const float* __restrict__ g3, const float* __restrict__ be3,
    const float* __restrict__ summed, const float* __restrict__ cnt,
    float* __restrict__ out, int N)
{
    __shared__ float sW2[129 * 64];
    __shared__ float sW3[64 * 64];
    __shared__ float sv[6 * 64];
    for (int t = threadIdx.x; t < 129 * 64; t += 256) sW2[t] = W2[t];
    for (int t = threadIdx.x; t < 64 * 64; t += 256) sW3[t] = W3[t];
    if (threadIdx.x < 64) {
        int j = threadIdx.x;
        sv[j]       = b2[j]; sv[64 + j]  = g2[j]; sv[128 + j] = be2[j];
        sv[192 + j] = b3[j]; sv[256 + j] = g3[j]; sv[320 + j] = be3[j];
    }
    __syncthreads();

    const float u0 = u[0];
    const int lane = threadIdx.x & 63;
    const int wid  = threadIdx.x >> 6;

    for (int n = blockIdx.x * 4 + wid; n < N; n += gridDim.x * 4) {
        float xv = x_h[(long)n * 64 + lane];
        float c  = fmaxf(cnt[n], 1.f);
        float av = summed[(long)n * 64 + lane] / c;

        float acc = sv[lane] + u0 * sW2[128 * 64 + lane];
        #pragma unroll
        for (int i = 0; i < 64; ++i) acc += __shfl(xv, i) * sW2[i * 64 + lane];
        #pragma unroll
        for (int i = 0; i < 64; ++i) acc += __shfl(av, i) * sW2[(64 + i) * 64 + lane];
        acc = fmaxf(acc, 0.f);
        float s1 = acc, s2 = acc * acc;
        #pragma unroll
        for (int m = 32; m; m >>= 1) { s1 += __shfl_xor(s1, m); s2 += __shfl_xor(s2, m); }
        float mu  = s1 * (1.f / 64.f);
        float var = s2 * (1.f / 64.f) - mu * mu;
        float h2 = (acc - mu) * rsqrtf(var + EPS) * sv[64 + lane] + sv[128 + lane];

        float acc3 = sv[192 + lane];
        #pragma unroll
        for (int i = 0; i < 64; ++i) acc3 += __shfl(h2, i) * sW3[i * 64 + lane];
        s1 = acc3; s2 = acc3 * acc3;
        #pragma unroll
        for (int m = 32; m; m >>= 1) { s1 += __shfl_xor(s1, m); s2 += __shfl_xor(s2, m); }
        mu  = s1 * (1.f / 64.f);
        var = s2 * (1.f / 64.f) - mu * mu;
        float h3 = (acc3 - mu) * rsqrtf(var + EPS) * sv[256 + lane] + sv[320 + lane];

        out[(long)n * 64 + lane] = h3 + xv;
    }
}

extern "C" void kernel_launch(void* const* d_in, const int* in_sizes, int n_in,
                              void* d_out, int out_size, void* d_ws, size_t ws_size,
                              hipStream_t stream)
{
    const float* x_h   = (const float*)d_in[0];
    const int*   eidx  = (const int*)  d_in[1];
    const float* eattr = (const float*)d_in[2];
    const float* u     = (const float*)d_in[3];
    // d_in[4] = batch (all zeros, B=1) -> unused
    const float* W1  = (const float*)d_in[5];
    const float* b1  = (const float*)d_in[6];
    const float* g1  = (const float*)d_in[7];
    const float* be1 = (const float*)d_in[8];
    const float* W2  = (const float*)d_in[9];
    const float* b2  = (const float*)d_in[10];
    const float* g2  = (const float*)d_in[11];
    const float* be2 = (const float*)d_in[12];
    const float* W3  = (const float*)d_in[13];
    const float* b3  = (const float*)d_in[14];
    const float* g3  = (const float*)d_in[15];
    const float* be3 = (const float*)d_in[16];

    const int N = in_sizes[0] / 64;
    const int E = in_sizes[1] / 2;

    float* summed = (float*)d_ws;                 // N*64 floats
    float* cnt    = summed + (size_t)N * 64;      // N floats

    long zn = (long)N * 64 + N;
    zero_kernel<<<1024, 256, 0, stream>>>(summed, zn);

    edge_kernel<<<2048, 256, 0, stream>>>(x_h, eidx, eattr, W1, b1, g1, be1,
                                          summed, cnt, E, N);

    node_kernel<<<1024, 256, 0, stream>>>(x_h, u, W2, b2, g2, be2, W3, b3, g3, be3,
                                          summed, cnt, (float*)d_out, N);
}

// Round 3
// 380.097 us; speedup vs baseline: 8.8106x; 2.6530x over previous
//
#include <hip/hip_runtime.h>

#define EPS 1e-5f

typedef __attribute__((ext_vector_type(8))) short short8v;
typedef __attribute__((ext_vector_type(4))) float f32x4;

__device__ __forceinline__ unsigned short f2bf(float f) {
    unsigned u = __builtin_bit_cast(unsigned, f);
    u += 0x7fffu + ((u >> 16) & 1u);
    return (unsigned short)(u >> 16);
}

// ---------------- zero workspace ----------------
__global__ __launch_bounds__(256) void zero_kernel(float* __restrict__ p, long n) {
    long i = (long)blockIdx.x * blockDim.x + threadIdx.x;
    long stride = (long)gridDim.x * blockDim.x;
    long n4 = n >> 2;
    float4* p4 = (float4*)p;
    for (long k = i; k < n4; k += stride) p4[k] = make_float4(0.f, 0.f, 0.f, 0.f);
    for (long k = (n4 << 2) + i; k < n; k += stride) p[k] = 0.f;
}

// ---------------- edge stage (MFMA, unchanged from round 2) ----------------
__global__ __launch_bounds__(256) void edge_kernel(
    const float* __restrict__ x_h, const int* __restrict__ eidx,
    const float* __restrict__ eattr,
    const float* __restrict__ W1, const float* __restrict__ b1,
    const float* __restrict__ g1, const float* __restrict__ be1,
    float* __restrict__ summed, float* __restrict__ cnt,
    int E, int N)
{
    const int lane = threadIdx.x & 63;
    const int wid  = threadIdx.x >> 6;
    const int c = lane & 15;
    const int q = lane >> 4;

    short8v w1f[4][4];
    #pragma unroll
    for (int ks = 0; ks < 4; ++ks) {
        #pragma unroll
        for (int nt = 0; nt < 4; ++nt) {
            int k0 = ks * 32 + q * 8;
            int n  = nt * 16 + c;
            short8v f;
            #pragma unroll
            for (int j = 0; j < 8; ++j) f[j] = (short)f2bf(W1[(k0 + j) * 64 + n]);
            w1f[ks][nt] = f;
        }
    }
    float b1v[4], g1v[4], bev[4];
    #pragma unroll
    for (int nt = 0; nt < 4; ++nt) {
        b1v[nt] = b1[nt * 16 + c];
        g1v[nt] = g1[nt * 16 + c];
        bev[nt] = be1[nt * 16 + c];
    }

    for (long e0 = (long)blockIdx.x * 256 + wid * 64; e0 < E; e0 += (long)gridDim.x * 256) {
        {
            long el = e0 + lane;
            if (el < E) atomicAdd(&cnt[eidx[E + el]], 1.f);
        }

        f32x4 acc[4][4];
        #pragma unroll
        for (int mt = 0; mt < 4; ++mt)
            #pragma unroll
            for (int nt = 0; nt < 4; ++nt)
                acc[mt][nt] = (f32x4){0.f, 0.f, 0.f, 0.f};

        #pragma unroll
        for (int mt = 0; mt < 4; ++mt) {
            long er = e0 + mt * 16 + c;
            long ec = (er < E) ? er : (E - 1);
            int src = eidx[ec];
            const float* xp = x_h + (long)src * 64;
            const float* ep = eattr + ec * 64;
            #pragma unroll
            for (int ks = 0; ks < 4; ++ks) {
                int k0 = ks * 32 + q * 8;
                const float* base = (ks < 2) ? (xp + k0) : (ep + (k0 - 64));
                float4 lo = *(const float4*)(base);
                float4 hi = *(const float4*)(base + 4);
                short8v a;
                a[0] = (short)f2bf(lo.x); a[1] = (short)f2bf(lo.y);
                a[2] = (short)f2bf(lo.z); a[3] = (short)f2bf(lo.w);
                a[4] = (short)f2bf(hi.x); a[5] = (short)f2bf(hi.y);
                a[6] = (short)f2bf(hi.z); a[7] = (short)f2bf(hi.w);
                #pragma unroll
                for (int nt = 0; nt < 4; ++nt)
                    acc[mt][nt] = __builtin_amdgcn_mfma_f32_16x16x32_bf16(
                        a, w1f[ks][nt], acc[mt][nt], 0, 0, 0);
            }
        }

        #pragma unroll
        for (int mt = 0; mt < 4; ++mt) {
            float s1[4] = {0, 0, 0, 0}, s2[4] = {0, 0, 0, 0};
            #pragma unroll
            for (int nt = 0; nt < 4; ++nt) {
                #pragma unroll
                for (int r = 0; r < 4; ++r) {
                    float f = fmaxf(acc[mt][nt][r] + b1v[nt], 0.f);
                    acc[mt][nt][r] = f;
                    s1[r] += f; s2[r] += f * f;
                }
            }
            #pragma unroll
            for (int m = 1; m <= 8; m <<= 1) {
                #pragma unroll
                for (int r = 0; r < 4; ++r) {
                    s1[r] += __shfl_xor(s1[r], m);
                    s2[r] += __shfl_xor(s2[r], m);
                }
            }
            float mu[4], rs[4]; int dst[4];
            #pragma unroll
            for (int r = 0; r < 4; ++r) {
                mu[r] = s1[r] * (1.f / 64.f);
                float var = s2[r] * (1.f / 64.f) - mu[r] * mu[r];
                rs[r] = rsqrtf(var + EPS);
                long er = e0 + mt * 16 + q * 4 + r;
                dst[r] = (er < E) ? eidx[E + er] : -1;
            }
            #pragma unroll
            for (int nt = 0; nt < 4; ++nt) {
                #pragma unroll
                for (int r = 0; r < 4; ++r) {
                    if (dst[r] >= 0) {
                        float outv = (acc[mt][nt][r] - mu[r]) * rs[r] * g1v[nt] + bev[nt];
                        atomicAdd(&summed[(long)dst[r] * 64 + nt * 16 + c], outv);
                    }
                }
            }
        }
    }
}

// ---------------- node stage (MFMA): h=LN(relu([x,agg,u]@W2+b2)); h=LN(h@W3+b3); out=h+x ----
// One wave per 64-node tile. Layer2 K=128 ([x|agg]; u-term folded into bias since B=1).
// h2 transposed C-frag -> A-frag through a per-wave LDS tile (rows padded to 72 bf16
// => 144B stride => 4-bank step => <=2-way conflicts, free).
__global__ __launch_bounds__(256) void node_kernel(
    const float* __restrict__ x_h, const float* __restrict__ u,
    const float* __restrict__ W2, const float* __restrict__ b2,
    const float* __restrict__ g2, const float* __restrict__ be2,
    const float* __restrict__ W3, const float* __restrict__ b3,
    const float* __restrict__ g3, const float* __restrict__ be3,
    const float* __restrict__ summed, const float* __restrict__ cnt,
    float* __restrict__ out, int N)
{
    __shared__ unsigned short sh[4][64][72];   // 36.9 KB, per-wave private tile

    const int lane = threadIdx.x & 63;
    const int wid  = threadIdx.x >> 6;
    const int c = lane & 15;
    const int q = lane >> 4;
    const float u0 = u[0];

    // B-frags: W2 rows 0..127 (K=128), W3 (K=64)
    short8v w2f[4][4], w3f[2][4];
    #pragma unroll
    for (int ks = 0; ks < 4; ++ks)
        #pragma unroll
        for (int nt = 0; nt < 4; ++nt) {
            int k0 = ks * 32 + q * 8;
            int n  = nt * 16 + c;
            short8v f;
            #pragma unroll
            for (int j = 0; j < 8; ++j) f[j] = (short)f2bf(W2[(k0 + j) * 64 + n]);
            w2f[ks][nt] = f;
        }
    #pragma unroll
    for (int ks = 0; ks < 2; ++ks)
        #pragma unroll
        for (int nt = 0; nt < 4; ++nt) {
            int k0 = ks * 32 + q * 8;
            int n  = nt * 16 + c;
            short8v f;
            #pragma unroll
            for (int j = 0; j < 8; ++j) f[j] = (short)f2bf(W3[(k0 + j) * 64 + n]);
            w3f[ks][nt] = f;
        }

    float b2p[4], g2v[4], be2v[4], b3v[4], g3v[4], be3v[4];
    #pragma unroll
    for (int nt = 0; nt < 4; ++nt) {
        int n = nt * 16 + c;
        b2p[nt] = b2[n] + u0 * W2[128 * 64 + n];   // fold u-row (batch==0, B==1)
        g2v[nt] = g2[n]; be2v[nt] = be2[n];
        b3v[nt] = b3[n]; g3v[nt] = g3[n]; be3v[nt] = be3[n];
    }

    const long n0 = ((long)blockIdx.x * 4 + wid) * 64;
    if (n0 >= N) return;

    // ---- layer 2 ----
    #pragma unroll
    for (int mt = 0; mt < 4; ++mt) {
        long nr = n0 + mt * 16 + c;
        long nc = (nr < N) ? nr : (N - 1);
        const float* xp = x_h + nc * 64;
        const float* sp = summed + nc * 64;
        float inv = 1.f / fmaxf(cnt[nc], 1.f);

        f32x4 acc[4];
        #pragma unroll
        for (int nt = 0; nt < 4; ++nt) acc[nt] = (f32x4){0.f, 0.f, 0.f, 0.f};

        #pragma unroll
        for (int ks = 0; ks < 4; ++ks) {
            int k0 = ks * 32 + q * 8;
            short8v a;
            if (ks < 2) {
                float4 lo = *(const float4*)(xp + k0);
                float4 hi = *(const float4*)(xp + k0 + 4);
                a[0] = (short)f2bf(lo.x); a[1] = (short)f2bf(lo.y);
                a[2] = (short)f2bf(lo.z); a[3] = (short)f2bf(lo.w);
                a[4] = (short)f2bf(hi.x); a[5] = (short)f2bf(hi.y);
                a[6] = (short)f2bf(hi.z); a[7] = (short)f2bf(hi.w);
            } else {
                float4 lo = *(const float4*)(sp + k0 - 64);
                float4 hi = *(const float4*)(sp + k0 - 60);
                a[0] = (short)f2bf(lo.x * inv); a[1] = (short)f2bf(lo.y * inv);
                a[2] = (short)f2bf(lo.z * inv); a[3] = (short)f2bf(lo.w * inv);
                a[4] = (short)f2bf(hi.x * inv); a[5] = (short)f2bf(hi.y * inv);
                a[6] = (short)f2bf(hi.z * inv); a[7] = (short)f2bf(hi.w * inv);
            }
            #pragma unroll
            for (int nt = 0; nt < 4; ++nt)
                acc[nt] = __builtin_amdgcn_mfma_f32_16x16x32_bf16(a, w2f[ks][nt], acc[nt], 0, 0, 0);
        }

        // bias + relu + LN -> write bf16 tile to LDS (transpose staging)
        float s1[4] = {0, 0, 0, 0}, s2[4] = {0, 0, 0, 0};
        #pragma unroll
        for (int nt = 0; nt < 4; ++nt)
            #pragma unroll
            for (int r = 0; r < 4; ++r) {
                float f = fmaxf(acc[nt][r] + b2p[nt], 0.f);
                acc[nt][r] = f;
                s1[r] += f; s2[r] += f * f;
            }
        #pragma unroll
        for (int m = 1; m <= 8; m <<= 1)
            #pragma unroll
            for (int r = 0; r < 4; ++r) {
                s1[r] += __shfl_xor(s1[r], m);
                s2[r] += __shfl_xor(s2[r], m);
            }
        #pragma unroll
        for (int r = 0; r < 4; ++r) {
            float mu = s1[r] * (1.f / 64.f);
            float var = s2[r] * (1.f / 64.f) - mu * mu;
            float rs = rsqrtf(var + EPS);
            #pragma unroll
            for (int nt = 0; nt < 4; ++nt) {
                float h2 = (acc[nt][r] - mu) * rs * g2v[nt] + be2v[nt];
                sh[wid][mt * 16 + q * 4 + r][nt * 16 + c] = f2bf(h2);
            }
        }
    }

    // ---- layer 3 (reads per-wave LDS tile; same-wave dependency, no barrier needed) ----
    #pragma unroll
    for (int mt = 0; mt < 4; ++mt) {
        f32x4 acc[4];
        #pragma unroll
        for (int nt = 0; nt < 4; ++nt) acc[nt] = (f32x4){0.f, 0.f, 0.f, 0.f};

        #pragma unroll
        for (int ks = 0; ks < 2; ++ks) {
            short8v a = *(const short8v*)&sh[wid][mt * 16 + c][ks * 32 + q * 8];
            #pragma unroll
            for (int nt = 0; nt < 4; ++nt)
                acc[nt] = __builtin_amdgcn_mfma_f32_16x16x32_bf16(a, w3f[ks][nt], acc[nt], 0, 0, 0);
        }

        float s1[4] = {0, 0, 0, 0}, s2[4] = {0, 0, 0, 0};
        #pragma unroll
        for (int nt = 0; nt < 4; ++nt)
            #pragma unroll
            for (int r = 0; r < 4; ++r) {
                float f = acc[nt][r] + b3v[nt];
                acc[nt][r] = f;
                s1[r] += f; s2[r] += f * f;
            }
        #pragma unroll
        for (int m = 1; m <= 8; m <<= 1)
            #pragma unroll
            for (int r = 0; r < 4; ++r) {
                s1[r] += __shfl_xor(s1[r], m);
                s2[r] += __shfl_xor(s2[r], m);
            }
        #pragma unroll
        for (int r = 0; r < 4; ++r) {
            float mu = s1[r] * (1.f / 64.f);
            float var = s2[r] * (1.f / 64.f) - mu * mu;
            float rs = rsqrtf(var + EPS);
            long node = n0 + mt * 16 + q * 4 + r;
            if (node < N) {
                #pragma unroll
                for (int nt = 0; nt < 4; ++nt) {
                    long off = node * 64 + nt * 16 + c;
                    float h3 = (acc[nt][r] - mu) * rs * g3v[nt] + be3v[nt];
                    out[off] = h3 + x_h[off];
                }
            }
        }
    }
}

extern "C" void kernel_launch(void* const* d_in, const int* in_sizes, int n_in,
                              void* d_out, int out_size, void* d_ws, size_t ws_size,
                              hipStream_t stream)
{
    const float* x_h   = (const float*)d_in[0];
    const int*   eidx  = (const int*)  d_in[1];
    const float* eattr = (const float*)d_in[2];
    const float* u     = (const float*)d_in[3];
    // d_in[4] = batch (all zeros, B=1) -> unused
    const float* W1  = (const float*)d_in[5];
    const float* b1  = (const float*)d_in[6];
    const float* g1  = (const float*)d_in[7];
    const float* be1 = (const float*)d_in[8];
    const float* W2  = (const float*)d_in[9];
    const float* b2  = (const float*)d_in[10];
    const float* g2  = (const float*)d_in[11];
    const float* be2 = (const float*)d_in[12];
    const float* W3  = (const float*)d_in[13];
    const float* b3  = (const float*)d_in[14];
    const float* g3  = (const float*)d_in[15];
    const float* be3 = (const float*)d_in[16];

    const int N = in_sizes[0] / 64;
    const int E = in_sizes[1] / 2;

    float* summed = (float*)d_ws;                 // N*64 floats
    float* cnt    = summed + (size_t)N * 64;      // N floats

    long zn = (long)N * 64 + N;
    zero_kernel<<<1024, 256, 0, stream>>>(summed, zn);

    edge_kernel<<<2048, 256, 0, stream>>>(x_h, eidx, eattr, W1, b1, g1, be1,
                                          summed, cnt, E, N);

    int nblocks = (N + 255) / 256;                // 4 waves/block, 64 nodes/wave
    node_kernel<<<nblocks, 256, 0, stream>>>(x_h, u, W2, b2, g2, be2, W3, b3, g3, be3,
                                             summed, cnt, (float*)d_out, N);
}

// Round 4
// 364.401 us; speedup vs baseline: 9.1901x; 1.0431x over previous
//
#include <hip/hip_runtime.h>

#define EPS 1e-5f

typedef __attribute__((ext_vector_type(8))) short short8v;
typedef __attribute__((ext_vector_type(4))) float f32x4;

__device__ __forceinline__ unsigned short f2bf(float f) {
    unsigned u = __builtin_bit_cast(unsigned, f);
    u += 0x7fffu + ((u >> 16) & 1u);
    return (unsigned short)(u >> 16);
}
__device__ __forceinline__ float bf2f(unsigned short h) {
    return __builtin_bit_cast(float, (unsigned)h << 16);
}

// ---------------- zero workspace (bytes, via float4) ----------------
__global__ __launch_bounds__(256) void zero_kernel(float* __restrict__ p, long n) {
    long i = (long)blockIdx.x * blockDim.x + threadIdx.x;
    long stride = (long)gridDim.x * blockDim.x;
    long n4 = n >> 2;
    float4* p4 = (float4*)p;
    for (long k = i; k < n4; k += stride) p4[k] = make_float4(0.f, 0.f, 0.f, 0.f);
    for (long k = (n4 << 2) + i; k < n; k += stride) p[k] = 0.f;
}

// ---------------- edge stage (MFMA, fused epilogue, pk_bf16 atomics) ----------------
// One wave per 64-edge tile iteration. Per mt (16 edges): gather A-frags, 16 MFMA,
// bias+relu+LN in-register, scatter via packed-bf16 atomics (even lanes, 2 feats/op).
__global__ __launch_bounds__(256) void edge_kernel(
    const float* __restrict__ x_h, const int* __restrict__ eidx,
    const float* __restrict__ eattr,
    const float* __restrict__ W1, const float* __restrict__ b1,
    const float* __restrict__ g1, const float* __restrict__ be1,
    unsigned short* __restrict__ summed, float* __restrict__ cnt,
    int E, int N)
{
    const int lane = threadIdx.x & 63;
    const int wid  = threadIdx.x >> 6;
    const int c = lane & 15;
    const int q = lane >> 4;

    // B fragments: W1[k][n] fp32 row-major [128][64]; lane holds k=ks*32+q*8+j, n=nt*16+c.
    short8v w1f[4][4];
    #pragma unroll
    for (int ks = 0; ks < 4; ++ks) {
        #pragma unroll
        for (int nt = 0; nt < 4; ++nt) {
            int k0 = ks * 32 + q * 8;
            int n  = nt * 16 + c;
            short8v f;
            #pragma unroll
            for (int j = 0; j < 8; ++j) f[j] = (short)f2bf(W1[(k0 + j) * 64 + n]);
            w1f[ks][nt] = f;
        }
    }
    float b1v[4], g1v[4], bev[4];
    #pragma unroll
    for (int nt = 0; nt < 4; ++nt) {
        b1v[nt] = b1[nt * 16 + c];
        g1v[nt] = g1[nt * 16 + c];
        bev[nt] = be1[nt * 16 + c];
    }

    for (long e0 = (long)blockIdx.x * 256 + wid * 64; e0 < E; e0 += (long)gridDim.x * 256) {
        // per-edge count atomic (one lane per edge, coalesced eidx load)
        {
            long el = e0 + lane;
            if (el < E) atomicAdd(&cnt[eidx[E + el]], 1.f);
        }

        #pragma unroll
        for (int mt = 0; mt < 4; ++mt) {
            long er = e0 + mt * 16 + c;
            long ec = (er < E) ? er : (E - 1);
            int src = eidx[ec];
            const float* xp = x_h + (long)src * 64;
            const float* ep = eattr + ec * 64;

            f32x4 acc[4];
            #pragma unroll
            for (int nt = 0; nt < 4; ++nt) acc[nt] = (f32x4){0.f, 0.f, 0.f, 0.f};

            #pragma unroll
            for (int ks = 0; ks < 4; ++ks) {
                int k0 = ks * 32 + q * 8;
                const float* base = (ks < 2) ? (xp + k0) : (ep + (k0 - 64));
                float4 lo = *(const float4*)(base);
                float4 hi = *(const float4*)(base + 4);
                short8v a;
                a[0] = (short)f2bf(lo.x); a[1] = (short)f2bf(lo.y);
                a[2] = (short)f2bf(lo.z); a[3] = (short)f2bf(lo.w);
                a[4] = (short)f2bf(hi.x); a[5] = (short)f2bf(hi.y);
                a[6] = (short)f2bf(hi.z); a[7] = (short)f2bf(hi.w);
                #pragma unroll
                for (int nt = 0; nt < 4; ++nt)
                    acc[nt] = __builtin_amdgcn_mfma_f32_16x16x32_bf16(
                        a, w1f[ks][nt], acc[nt], 0, 0, 0);
            }

            // epilogue: bias + relu + LayerNorm (row = edge) + packed-bf16 atomic scatter
            float s1[4] = {0, 0, 0, 0}, s2[4] = {0, 0, 0, 0};
            #pragma unroll
            for (int nt = 0; nt < 4; ++nt) {
                #pragma unroll
                for (int r = 0; r < 4; ++r) {
                    float f = fmaxf(acc[nt][r] + b1v[nt], 0.f);
                    acc[nt][r] = f;
                    s1[r] += f; s2[r] += f * f;
                }
            }
            #pragma unroll
            for (int m = 1; m <= 8; m <<= 1) {
                #pragma unroll
                for (int r = 0; r < 4; ++r) {
                    s1[r] += __shfl_xor(s1[r], m);
                    s2[r] += __shfl_xor(s2[r], m);
                }
            }
            float mu[4], rs[4]; int dst[4];
            #pragma unroll
            for (int r = 0; r < 4; ++r) {
                mu[r] = s1[r] * (1.f / 64.f);
                float var = s2[r] * (1.f / 64.f) - mu[r] * mu[r];
                rs[r] = rsqrtf(var + EPS);
                long er2 = e0 + mt * 16 + q * 4 + r;
                dst[r] = (er2 < E) ? eidx[E + er2] : -1;   // broadcast load (16 lanes share addr)
            }
            #pragma unroll
            for (int nt = 0; nt < 4; ++nt) {
                #pragma unroll
                for (int r = 0; r < 4; ++r) {
                    float outv = (acc[nt][r] - mu[r]) * rs[r] * g1v[nt] + bev[nt];
                    float nb = __shfl_xor(outv, 1);   // neighbor feature (c^1), all lanes exec
                    if (dst[r] >= 0 && !(c & 1)) {
                        unsigned pk = (unsigned)f2bf(outv) | ((unsigned)f2bf(nb) << 16);
                        unsigned long long a64 = (unsigned long long)
                            (summed + (long)dst[r] * 64 + nt * 16 + c);
                        asm volatile("global_atomic_pk_add_bf16 %0, %1, off"
                                     :: "v"(a64), "v"(pk) : "memory");
                    }
                }
            }
        }
    }
}

// ---------------- node stage (MFMA): h=LN(relu([x,agg,u]@W2+b2)); h=LN(h@W3+b3); out=h+x ----
__global__ __launch_bounds__(256) void node_kernel(
    const float* __restrict__ x_h, const float* __restrict__ u,
    const float* __restrict__ W2, const float* __restrict__ b2,
    const float* __restrict__ g2, const float* __restrict__ be2,
    const float* __restrict__ W3, const float* __restrict__ b3,
    const float* __restrict__ g3, const float* __restrict__ be3,
    const unsigned short* __restrict__ summed, const float* __restrict__ cnt,
    float* __restrict__ out, int N)
{
    __shared__ unsigned short sh[4][64][72];   // 36.9 KB, per-wave private tile

    const int lane = threadIdx.x & 63;
    const int wid  = threadIdx.x >> 6;
    const int c = lane & 15;
    const int q = lane >> 4;
    const float u0 = u[0];

    short8v w2f[4][4], w3f[2][4];
    #pragma unroll
    for (int ks = 0; ks < 4; ++ks)
        #pragma unroll
        for (int nt = 0; nt < 4; ++nt) {
            int k0 = ks * 32 + q * 8;
            int n  = nt * 16 + c;
            short8v f;
            #pragma unroll
            for (int j = 0; j < 8; ++j) f[j] = (short)f2bf(W2[(k0 + j) * 64 + n]);
            w2f[ks][nt] = f;
        }
    #pragma unroll
    for (int ks = 0; ks < 2; ++ks)
        #pragma unroll
        for (int nt = 0; nt < 4; ++nt) {
            int k0 = ks * 32 + q * 8;
            int n  = nt * 16 + c;
            short8v f;
            #pragma unroll
            for (int j = 0; j < 8; ++j) f[j] = (short)f2bf(W3[(k0 + j) * 64 + n]);
            w3f[ks][nt] = f;
        }

    float b2p[4], g2v[4], be2v[4], b3v[4], g3v[4], be3v[4];
    #pragma unroll
    for (int nt = 0; nt < 4; ++nt) {
        int n = nt * 16 + c;
        b2p[nt] = b2[n] + u0 * W2[128 * 64 + n];   // fold u-row (batch==0, B==1)
        g2v[nt] = g2[n]; be2v[nt] = be2[n];
        b3v[nt] = b3[n]; g3v[nt] = g3[n]; be3v[nt] = be3[n];
    }

    const long n0 = ((long)blockIdx.x * 4 + wid) * 64;
    if (n0 >= N) return;

    // ---- layer 2 ----
    #pragma unroll
    for (int mt = 0; mt < 4; ++mt) {
        long nr = n0 + mt * 16 + c;
        long nc = (nr < N) ? nr : (N - 1);
        const float* xp = x_h + nc * 64;
        const unsigned short* sp = summed + nc * 64;
        float inv = 1.f / fmaxf(cnt[nc], 1.f);

        f32x4 acc[4];
        #pragma unroll
        for (int nt = 0; nt < 4; ++nt) acc[nt] = (f32x4){0.f, 0.f, 0.f, 0.f};

        #pragma unroll
        for (int ks = 0; ks < 4; ++ks) {
            int k0 = ks * 32 + q * 8;
            short8v a;
            if (ks < 2) {
                float4 lo = *(const float4*)(xp + k0);
                float4 hi = *(const float4*)(xp + k0 + 4);
                a[0] = (short)f2bf(lo.x); a[1] = (short)f2bf(lo.y);
                a[2] = (short)f2bf(lo.z); a[3] = (short)f2bf(lo.w);
                a[4] = (short)f2bf(hi.x); a[5] = (short)f2bf(hi.y);
                a[6] = (short)f2bf(hi.z); a[7] = (short)f2bf(hi.w);
            } else {
                short8v raw = *(const short8v*)(sp + (k0 - 64));
                #pragma unroll
                for (int j = 0; j < 8; ++j)
                    a[j] = (short)f2bf(bf2f((unsigned short)raw[j]) * inv);
            }
            #pragma unroll
            for (int nt = 0; nt < 4; ++nt)
                acc[nt] = __builtin_amdgcn_mfma_f32_16x16x32_bf16(a, w2f[ks][nt], acc[nt], 0, 0, 0);
        }

        float s1[4] = {0, 0, 0, 0}, s2[4] = {0, 0, 0, 0};
        #pragma unroll
        for (int nt = 0; nt < 4; ++nt)
            #pragma unroll
            for (int r = 0; r < 4; ++r) {
                float f = fmaxf(acc[nt][r] + b2p[nt], 0.f);
                acc[nt][r] = f;
                s1[r] += f; s2[r] += f * f;
            }
        #pragma unroll
        for (int m = 1; m <= 8; m <<= 1)
            #pragma unroll
            for (int r = 0; r < 4; ++r) {
                s1[r] += __shfl_xor(s1[r], m);
                s2[r] += __shfl_xor(s2[r], m);
            }
        #pragma unroll
        for (int r = 0; r < 4; ++r) {
            float mu = s1[r] * (1.f / 64.f);
            float var = s2[r] * (1.f / 64.f) - mu * mu;
            float rs = rsqrtf(var + EPS);
            #pragma unroll
            for (int nt = 0; nt < 4; ++nt) {
                float h2 = (acc[nt][r] - mu) * rs * g2v[nt] + be2v[nt];
                sh[wid][mt * 16 + q * 4 + r][nt * 16 + c] = f2bf(h2);
            }
        }
    }

    // ---- layer 3 (per-wave LDS tile; same-wave dependency, no barrier needed) ----
    #pragma unroll
    for (int mt = 0; mt < 4; ++mt) {
        f32x4 acc[4];
        #pragma unroll
        for (int nt = 0; nt < 4; ++nt) acc[nt] = (f32x4){0.f, 0.f, 0.f, 0.f};

        #pragma unroll
        for (int ks = 0; ks < 2; ++ks) {
            short8v a = *(const short8v*)&sh[wid][mt * 16 + c][ks * 32 + q * 8];
            #pragma unroll
            for (int nt = 0; nt < 4; ++nt)
                acc[nt] = __builtin_amdgcn_mfma_f32_16x16x32_bf16(a, w3f[ks][nt], acc[nt], 0, 0, 0);
        }

        float s1[4] = {0, 0, 0, 0}, s2[4] = {0, 0, 0, 0};
        #pragma unroll
        for (int nt = 0; nt < 4; ++nt)
            #pragma unroll
            for (int r = 0; r < 4; ++r) {
                float f = acc[nt][r] + b3v[nt];
                acc[nt][r] = f;
                s1[r] += f; s2[r] += f * f;
            }
        #pragma unroll
        for (int m = 1; m <= 8; m <<= 1)
            #pragma unroll
            for (int r = 0; r < 4; ++r) {
                s1[r] += __shfl_xor(s1[r], m);
                s2[r] += __shfl_xor(s2[r], m);
            }
        #pragma unroll
        for (int r = 0; r < 4; ++r) {
            float mu = s1[r] * (1.f / 64.f);
            float var = s2[r] * (1.f / 64.f) - mu * mu;
            float rs = rsqrtf(var + EPS);
            long node = n0 + mt * 16 + q * 4 + r;
            if (node < N) {
                #pragma unroll
                for (int nt = 0; nt < 4; ++nt) {
                    long off = node * 64 + nt * 16 + c;
                    float h3 = (acc[nt][r] - mu) * rs * g3v[nt] + be3v[nt];
                    out[off] = h3 + x_h[off];
                }
            }
        }
    }
}

extern "C" void kernel_launch(void* const* d_in, const int* in_sizes, int n_in,
                              void* d_out, int out_size, void* d_ws, size_t ws_size,
                              hipStream_t stream)
{
    const float* x_h   = (const float*)d_in[0];
    const int*   eidx  = (const int*)  d_in[1];
    const float* eattr = (const float*)d_in[2];
    const float* u     = (const float*)d_in[3];
    // d_in[4] = batch (all zeros, B=1) -> unused
    const float* W1  = (const float*)d_in[5];
    const float* b1  = (const float*)d_in[6];
    const float* g1  = (const float*)d_in[7];
    const float* be1 = (const float*)d_in[8];
    const float* W2  = (const float*)d_in[9];
    const float* b2  = (const float*)d_in[10];
    const float* g2  = (const float*)d_in[11];
    const float* be2 = (const float*)d_in[12];
    const float* W3  = (const float*)d_in[13];
    const float* b3  = (const float*)d_in[14];
    const float* g3  = (const float*)d_in[15];
    const float* be3 = (const float*)d_in[16];

    const int N = in_sizes[0] / 64;
    const int E = in_sizes[1] / 2;

    unsigned short* summed = (unsigned short*)d_ws;              // N*64 bf16 (N*128 bytes)
    float* cnt = (float*)((char*)d_ws + (size_t)N * 128);        // N floats

    long zn = (long)N * 32 + N;     // floats covering summed(bf16) + cnt
    zero_kernel<<<1024, 256, 0, stream>>>((float*)d_ws, zn);

    edge_kernel<<<2048, 256, 0, stream>>>(x_h, eidx, eattr, W1, b1, g1, be1,
                                          summed, cnt, E, N);

    int nblocks = (N + 255) / 256;                // 4 waves/block, 64 nodes/wave
    node_kernel<<<nblocks, 256, 0, stream>>>(x_h, u, W2, b2, g2, be2, W3, b3, g3, be3,
                                             summed, cnt, (float*)d_out, N);
}